// Round 2
// baseline (1093.861 us; speedup 1.0000x reference)
//
#include <hip/hip_runtime.h>
#include <float.h>
#include <math.h>

#define TOKENS 16384
#define DIM    7168
#define NEXP   256
#define BM     64
#define BK     32
#define NCHUNK (DIM / BK)   // 224
#define NGROUP (NCHUNK / 4) // 56 groups of 4 chunks
#define ROUTE_SCALE 2.5
#define TAU      6e-6f      // ~50x rms score error of the fp16-split path
#define WSCALE   1024.0f    // lifts W_lo out of fp16 denormal range (exact pow2)
#define WUNSCALE 0.0009765625f

typedef _Float16 half8  __attribute__((ext_vector_type(8)));
typedef _Float16 half4v __attribute__((ext_vector_type(4)));
typedef float    f32x4  __attribute__((ext_vector_type(4)));

#define WPLANE 1835008      // 256*7168 halves per plane

__device__ __forceinline__ _Float16 hi16(float f) { return (_Float16)f; }
__device__ __forceinline__ _Float16 lo16(float f) {
    _Float16 h = (_Float16)f;
    return (_Float16)(f - (float)h);
}

// ---------------- Kernel 0: split (W*1024) into fp16 hi/lo planes, CHUNK-MAJOR ----------------
// Layout: plane[(k>>5)*8192 + e*32 + (k&31)] -> per K-chunk, all 256 experts contiguous.
__global__ __launch_bounds__(256)
void conv_w(const float* __restrict__ W, _Float16* __restrict__ Wh, _Float16* __restrict__ Wl) {
    int i = blockIdx.x * 256 + threadIdx.x;       // over 458752 float4s (exact)
    int f = i * 4;
    int e = f / DIM;
    int k = f - e * DIM;
    float4 v = ((const float4*)W)[i];
    v.x *= WSCALE; v.y *= WSCALE; v.z *= WSCALE; v.w *= WSCALE;
    half4v h, l;
    h[0] = hi16(v.x); l[0] = lo16(v.x);
    h[1] = hi16(v.y); l[1] = lo16(v.y);
    h[2] = hi16(v.z); l[2] = lo16(v.z);
    h[3] = hi16(v.w); l[3] = lo16(v.w);
    int o = ((k >> 5) << 13) + (e << 5) + (k & 31);   // chunk-major offset
    *(half4v*)(Wh + o) = h;
    *(half4v*)(Wl + o) = l;
}

// ---------------- asm pipeline primitives (T3/T4: pinned issue order, counted waits) ----------------
#define MFMA16(a, b, c) __builtin_amdgcn_mfma_f32_16x16x32_f16(a, b, c, 0, 0, 0)

// counted vmcnt wait + full scheduling fence (rule #18: fence required after asm waits)
#define VWAIT(n) do { \
    asm volatile("s_waitcnt vmcnt(" #n ")" ::: "memory"); \
    __builtin_amdgcn_sched_barrier(0); \
} while (0)

// 4 x dwordx4 W-chunk load into a named register set; asm volatile => issue order pinned
#define ISSUE_W(c, BH0, BH1, BL0, BL1) do { \
    const _Float16* _p0 = wph0 + (size_t)(c) * 8192; \
    const _Float16* _p1 = wph1 + (size_t)(c) * 8192; \
    const _Float16* _q0 = wpl0 + (size_t)(c) * 8192; \
    const _Float16* _q1 = wpl1 + (size_t)(c) * 8192; \
    asm volatile("global_load_dwordx4 %0, %1, off" : "=&v"(BH0) : "v"(_p0)); \
    asm volatile("global_load_dwordx4 %0, %1, off" : "=&v"(BH1) : "v"(_p1)); \
    asm volatile("global_load_dwordx4 %0, %1, off" : "=&v"(BL0) : "v"(_q0)); \
    asm volatile("global_load_dwordx4 %0, %1, off" : "=&v"(BL1) : "v"(_q1)); \
} while (0)

#define ISSUE_X(gg) do { \
    const float* _px = xsrc + (size_t)(gg) * 128; \
    asm volatile("global_load_dwordx4 %0, %1, off"           : "=&v"(xa) : "v"(_px)); \
    asm volatile("global_load_dwordx4 %0, %1, off offset:16" : "=&v"(xb) : "v"(_px)); \
} while (0)

// ds_read A-frags + 12 MFMA, identical per-accumulator product order to verified kernel
#define COMPUTE(ABP, BH0, BH1, BL0, BL1) do { \
    const _Float16* _ab = (ABP); \
    half8 ah0 = *(const half8*)(_ab + abase0); \
    half8 ah1 = *(const half8*)(_ab + abase1); \
    half8 al0 = *(const half8*)(_ab + 2048 + abase0); \
    half8 al1 = *(const half8*)(_ab + 2048 + abase1); \
    acc00 = MFMA16(ah0, BH0, acc00); acc00 = MFMA16(ah0, BL0, acc00); acc00 = MFMA16(al0, BH0, acc00); \
    acc01 = MFMA16(ah0, BH1, acc01); acc01 = MFMA16(ah0, BL1, acc01); acc01 = MFMA16(al0, BH1, acc01); \
    acc10 = MFMA16(ah1, BH0, acc10); acc10 = MFMA16(ah1, BL0, acc10); acc10 = MFMA16(al1, BH0, acc10); \
    acc11 = MFMA16(ah1, BH1, acc11); acc11 = MFMA16(ah1, BL1, acc11); acc11 = MFMA16(al1, BH1, acc11); \
} while (0)

#define DUMPF() do { \
    accf00 += acc00; acc00 = (f32x4)(0.0f); \
    accf01 += acc01; acc01 = (f32x4)(0.0f); \
    accf10 += acc10; acc10 = (f32x4)(0.0f); \
    accf11 += acc11; acc11 = (f32x4)(0.0f); \
} while (0)

#define CONVERT_WRITE_X(dstbuf) do { \
    half8 h8, l8; \
    const float v[8] = {xa.x, xa.y, xa.z, xa.w, xb.x, xb.y, xb.z, xb.w}; \
    _Pragma("unroll") \
    for (int e = 0; e < 8; ++e) { h8[e] = hi16(v[e]); l8[e] = lo16(v[e]); } \
    _Float16* d = hb + (dstbuf) * 16384 + xdst; \
    *(half8*)(d)        = h8; \
    *(half8*)(d + 2048) = l8; \
} while (0)

// ---------------- Kernel 1: fp16-split MFMA GEMM + routing + flags ----------------
// 1024 threads (16 waves), [64 tokens] x [256 experts] per block, grid 256.
// ALL main-loop VMEM is inline-asm (issue order pinned, compiler cannot sink prefetches or
// insert vmcnt(0) drains). Static in-flight schedule per 4-chunk group:
//   cc0: VWAIT(0)  [W(c0) only in flight]   -> issue W(c0+1), issue X(g+1)
//   cc1: VWAIT(2)  [W(c0+1) done, X kept]   -> issue W(c0+2)
//   cc2: VWAIT(0)  [W(c0+2)+X done, 2-chunk X cover] -> issue W(c0+3)
//   cc3: VWAIT(0)  [W(c0+3) done]           -> issue W(next c0), convert X, lgkm-only barrier
// W loads stay in flight across the raw s_barrier (T4). Per-(t,e) product order and accf
// cadence identical to verified kernel -> logits bit-identical -> gate_fix unchanged.
__global__ __launch_bounds__(1024)
void gate_main(const float* __restrict__ X, const _Float16* __restrict__ Wh,
               const _Float16* __restrict__ Wl, const float* __restrict__ Bp,
               float* __restrict__ outw, float* __restrict__ outi,
               unsigned char* __restrict__ flags) {
    __shared__ float smem[16384];                 // 64 KB: X dbuf (2 x 32 KB); routing overlay after
    _Float16* hb = (_Float16*)smem;

    const int tid  = threadIdx.x;
    const int lane = tid & 63;
    const int wid  = tid >> 6;                    // 0..15
    const int mh   = wid >> 3;                    // 0..1  (token half: 32 rows)
    const int ns   = wid & 7;                     // 0..7  (expert slice: 32 cols)
    const int m0   = blockIdx.x * BM;
    const int fr   = lane & 15;
    const int fk   = lane >> 4;                   // 0..3

    // X staging map: thread -> (chunk-in-group, row, 16B slot); XOR-swizzled dest
    const int xcc = tid >> 8;                     // 0..3
    const int xr  = (tid >> 2) & 63;              // 0..63
    const int xs  = tid & 3;                      // 0..3
    const float* xsrc = X + (size_t)(m0 + xr) * DIM + xcc * 32 + xs * 8;
    const int xdst = xcc * 4096 + xr * 32 + ((xs ^ ((xr >> 1) & 3)) << 3);

    // A-fragment LDS bases (halves), swizzled
    const int row0 = mh * 32 + fr;
    const int row1 = mh * 32 + 16 + fr;
    const int abase0 = row0 * 32 + ((fk ^ ((row0 >> 1) & 3)) << 3);
    const int abase1 = row1 * 32 + ((fk ^ ((row1 >> 1) & 3)) << 3);

    // W chunk-major per-lane base pointers; chunk c lives at +c*8192 halves
    const int wro = ((ns * 32 + fr) << 5) + fk * 8;
    const _Float16* wph0 = Wh + wro;
    const _Float16* wph1 = Wh + wro + 512;        // +16 experts * 32 halves
    const _Float16* wpl0 = Wl + wro;
    const _Float16* wpl1 = Wl + wro + 512;

    f32x4 acc00 = {}, acc01 = {}, acc10 = {}, acc11 = {};
    f32x4 accf00 = {}, accf01 = {}, accf10 = {}, accf11 = {};
    half8 bhA0, bhA1, blA0, blA1;                 // W register set A (even chunks)
    half8 bhB0, bhB1, blB0, blB1;                 // W register set B (odd chunks)
    float4 xa, xb;

    // ---- prologue: stage X group 0 (plain C++, compiler-managed waits); then pin W(c0) ----
    {
        float4 pa = *(const float4*)(xsrc);
        float4 pb = *(const float4*)(xsrc + 4);
        half8 h8, l8;
        const float v[8] = {pa.x, pa.y, pa.z, pa.w, pb.x, pb.y, pb.z, pb.w};
        #pragma unroll
        for (int e = 0; e < 8; ++e) { h8[e] = hi16(v[e]); l8[e] = lo16(v[e]); }
        *(half8*)(hb + xdst)        = h8;
        *(half8*)(hb + xdst + 2048) = l8;
    }
    ISSUE_W(0, bhA0, bhA1, blA0, blA1);           // in flight entering loop: [A(c=0)]
    asm volatile("s_waitcnt lgkmcnt(0)" ::: "memory");
    __builtin_amdgcn_s_barrier();

    for (int g = 0; g < NGROUP - 1; ++g) {        // groups 0..54 (full pipeline)
        const _Float16* ab = hb + (g & 1) * 16384;
        const int c0 = g * 4;
        // cc0
        VWAIT(0);                                 // A(c0) ready
        ISSUE_W(c0 + 1, bhB0, bhB1, blB0, blB1);
        ISSUE_X(g + 1);
        COMPUTE(ab, bhA0, bhA1, blA0, blA1);
        // cc1
        VWAIT(2);                                 // B(c0+1) ready; X stays in flight
        ISSUE_W(c0 + 2, bhA0, bhA1, blA0, blA1);
        COMPUTE(ab + 4096, bhB0, bhB1, blB0, blB1);
        // cc2
        VWAIT(0);                                 // A(c0+2) ready; forces X (2-chunk cover)
        ISSUE_W(c0 + 3, bhB0, bhB1, blB0, blB1);
        COMPUTE(ab + 8192, bhA0, bhA1, blA0, blA1);
        // cc3
        VWAIT(0);                                 // B(c0+3) ready
        ISSUE_W(c0 + 4, bhA0, bhA1, blA0, blA1);  // next group's c0
        COMPUTE(ab + 12288, bhB0, bhB1, blB0, blB1);
        if ((g & 3) == 3) DUMPF();                // fp32 master dump every 16 chunks (same cadence)
        CONVERT_WRITE_X((g & 1) ^ 1);             // X for group g+1 (xa/xb forced done at cc2)
        asm volatile("s_waitcnt lgkmcnt(0)" ::: "memory");
        __builtin_amdgcn_s_barrier();             // raw barrier: W loads stay in flight (T4)
    }
    {   // ---- epilogue group 55 (chunks 220..223, buf 1), no X issue, no prefetch past end ----
        const _Float16* ab = hb + 16384;
        VWAIT(0);                                 // A(220) ready
        ISSUE_W(221, bhB0, bhB1, blB0, blB1);
        COMPUTE(ab, bhA0, bhA1, blA0, blA1);
        VWAIT(0);
        ISSUE_W(222, bhA0, bhA1, blA0, blA1);
        COMPUTE(ab + 4096, bhB0, bhB1, blB0, blB1);
        VWAIT(0);
        ISSUE_W(223, bhB0, bhB1, blB0, blB1);
        COMPUTE(ab + 8192, bhA0, bhA1, blA0, blA1);
        VWAIT(0);
        COMPUTE(ab + 12288, bhB0, bhB1, blB0, blB1);
        DUMPF();                                  // g=55: (55&3)==3 -> same cadence
    }
    __syncthreads();                              // full drain before LDS overlay reuse

    // ---- logits (unscaled) to rotated LDS overlay ----
    float* lg = smem;                             // [64][256], word = t*256 + ((e+t)&255)
    {
        f32x4 af[2][2] = {{accf00, accf01}, {accf10, accf11}};
        #pragma unroll
        for (int m = 0; m < 2; ++m)
            #pragma unroll
            for (int n = 0; n < 2; ++n)
                #pragma unroll
                for (int r = 0; r < 4; ++r) {
                    int t = mh * 32 + m * 16 + fk * 4 + r;   // D row = (lane>>4)*4 + reg
                    int e = ns * 32 + n * 16 + fr;           // D col = lane&15
                    lg[t * 256 + ((e + t) & 255)] = af[m][n][r] * WUNSCALE;
                }
    }
    __syncthreads();

    // ---- fp32 routing + margin flags: one thread per token (R4/R7-verified, verbatim) ----
    if (tid < BM) {
        const int t = tid;
        const int gtok = m0 + t;
        float* row = lg + t * 256;

        for (int e = 0; e < 256; ++e) {
            int a = (e + t) & 255;
            row[a] = 1.0f / (1.0f + expf(-row[a]));
        }
        float gs[8];
        #pragma unroll
        for (int g = 0; g < 8; ++g) {
            float m1 = -FLT_MAX, m2 = -FLT_MAX;
            for (int e = g * 32; e < g * 32 + 32; ++e) {
                float v = row[(e + t) & 255] + Bp[e];
                if (v > m1) { m2 = m1; m1 = v; }
                else if (v > m2) { m2 = v; }
            }
            gs[g] = m1 + m2;
        }
        unsigned sel = 0;
        #pragma unroll
        for (int r = 0; r < 4; ++r) {
            float best = -FLT_MAX; int bg = 0;
            #pragma unroll
            for (int g = 0; g < 8; ++g)
                if (!((sel >> g) & 1) && gs[g] > best) { best = gs[g]; bg = g; }
            sel |= 1u << bg;
        }
        float selmin = FLT_MAX, unselmax = -FLT_MAX;
        #pragma unroll
        for (int g = 0; g < 8; ++g) {
            if ((sel >> g) & 1) selmin = fminf(selmin, gs[g]);
            else                unselmax = fmaxf(unselmax, gs[g]);
        }
        bool flag = (selmin - unselmax) < (2.0f * TAU);

        float pv = FLT_MAX; int pe = -1;
        float wv8[8]; int ie8[8]; float wsum = 0.f;
        for (int j = 0; j < 9; ++j) {
            float best = -FLT_MAX; int be = 0;
            for (int e = 0; e < 256; ++e) {
                float v = ((sel >> (e >> 5)) & 1) ? (row[(e + t) & 255] + Bp[e]) : 0.0f;
                bool after = (v < pv) || (v == pv && e > pe);
                if (after && v > best) { best = v; be = e; }
            }
            if (j > 0) flag = flag || ((pv - best) < TAU);
            if (j < 8) {
                float ow = row[(be + t) & 255];
                wv8[j] = ow; ie8[j] = be; wsum += ow;
            }
            pv = best; pe = be;
        }
        flags[gtok] = flag ? 1 : 0;
        float scale = (float)ROUTE_SCALE / wsum;
        #pragma unroll
        for (int j = 0; j < 8; ++j) {
            outw[(size_t)gtok * 8 + j] = wv8[j] * scale;
            outi[(size_t)gtok * 8 + j] = (float)ie8[j];
        }
    }
}

// ---------------- Kernel 2: fp64 recheck of flagged tokens (coalesced, R5/R7-verified) ----------------
__global__ __launch_bounds__(256)
void gate_fix(const float* __restrict__ X, const float* __restrict__ W,
              const float* __restrict__ Bp, float* __restrict__ outw,
              float* __restrict__ outi, const unsigned char* __restrict__ flags) {
    const int t = blockIdx.x;
    if (!flags[t]) return;
    __shared__ float  xrow[DIM];
    __shared__ double sig[NEXP];
    const int tid = threadIdx.x;
    const int s   = tid >> 5;
    const int kt  = tid & 31;

    for (int i = tid * 4; i < DIM; i += 1024)
        *(float4*)(xrow + i) = *(const float4*)(X + (size_t)t * DIM + i);
    __syncthreads();

    for (int i = 0; i < 32; ++i) {
        const int e = i * 8 + s;
        const float* wrow = W + (size_t)e * DIM;
        double s0 = 0, s1 = 0, s2 = 0, s3 = 0;
        for (int c = 0; c < DIM / 128; ++c) {
            int k = c * 128 + kt * 4;
            float4 w4 = *(const float4*)(wrow + k);
            float4 x4 = *(const float4*)(xrow + k);
            s0 = fma((double)x4.x, (double)w4.x, s0);
            s1 = fma((double)x4.y, (double)w4.y, s1);
            s2 = fma((double)x4.z, (double)w4.z, s2);
            s3 = fma((double)x4.w, (double)w4.w, s3);
        }
        double d = (s0 + s1) + (s2 + s3);
        #pragma unroll
        for (int m = 16; m >= 1; m >>= 1)
            d += __shfl_xor(d, m, 32);
        if (kt == 0) sig[e] = 1.0 / (1.0 + exp(-d));
    }
    __syncthreads();

    if (tid == 0) {
        const double* row = sig;
        double gs[8];
        #pragma unroll
        for (int g = 0; g < 8; ++g) {
            double m1 = -DBL_MAX, m2 = -DBL_MAX;
            for (int e = g * 32; e < g * 32 + 32; ++e) {
                double v = row[e] + (double)Bp[e];
                if (v > m1) { m2 = m1; m1 = v; }
                else if (v > m2) { m2 = v; }
            }
            gs[g] = m1 + m2;
        }
        unsigned sel = 0;
        #pragma unroll
        for (int r = 0; r < 4; ++r) {
            double best = -DBL_MAX; int bg = 0;
            #pragma unroll
            for (int g = 0; g < 8; ++g)
                if (!((sel >> g) & 1) && gs[g] > best) { best = gs[g]; bg = g; }
            sel |= 1u << bg;
        }
        double pv = DBL_MAX; int pe = -1;
        double wv8[8]; int ie8[8]; double wsum = 0.0;
        #pragma unroll
        for (int j = 0; j < 8; ++j) {
            double best = -DBL_MAX; int be = 0;
            for (int e = 0; e < 256; ++e) {
                double v = ((sel >> (e >> 5)) & 1) ? (row[e] + (double)Bp[e]) : 0.0;
                bool after = (v < pv) || (v == pv && e > pe);
                if (after && v > best) { best = v; be = e; }
            }
            double ow = row[be];
            wv8[j] = ow; ie8[j] = be; wsum += ow;
            pv = best; pe = be;
        }
        #pragma unroll
        for (int j = 0; j < 8; ++j) {
            outw[(size_t)t * 8 + j] = (float)((wv8[j] / wsum) * ROUTE_SCALE);
            outi[(size_t)t * 8 + j] = (float)ie8[j];
        }
    }
}

extern "C" void kernel_launch(void* const* d_in, const int* in_sizes, int n_in,
                              void* d_out, int out_size, void* d_ws, size_t ws_size,
                              hipStream_t stream) {
    const float* X  = (const float*)d_in[0];
    const float* W  = (const float*)d_in[1];
    const float* Bp = (const float*)d_in[2];
    float* outw = (float*)d_out;
    float* outi = (float*)d_out + (size_t)TOKENS * 8;

    _Float16* Wh = (_Float16*)d_ws;                          // 3.67 MB (chunk-major)
    _Float16* Wl = Wh + WPLANE;                              // 3.67 MB (chunk-major)
    unsigned char* flags = (unsigned char*)(Wl + WPLANE);    // 16 KB

    conv_w   <<<dim3(WPLANE / 1024), dim3(256),  0, stream>>>(W, Wh, Wl);
    gate_main<<<dim3(TOKENS / BM),   dim3(1024), 0, stream>>>(X, Wh, Wl, Bp, outw, outi, flags);
    gate_fix <<<dim3(TOKENS),        dim3(256),  0, stream>>>(X, W, Bp, outw, outi, flags);
}

// Round 3
// 1085.273 us; speedup vs baseline: 1.0079x; 1.0079x over previous
//
#include <hip/hip_runtime.h>
#include <float.h>
#include <math.h>

#define TOKENS 16384
#define DIM    7168
#define NEXP   256
#define BM     64
#define BK     32
#define NCHUNK (DIM / BK)   // 224
#define NGROUP (NCHUNK / 4) // 56 groups of 4 chunks
#define ROUTE_SCALE 2.5
#define TAU      6e-6f      // ~50x rms score error of the fp16-split path
#define WSCALE   1024.0f    // lifts W_lo out of fp16 denormal range (exact pow2)
#define WUNSCALE 0.0009765625f

typedef _Float16 half8  __attribute__((ext_vector_type(8)));
typedef _Float16 half4v __attribute__((ext_vector_type(4)));
typedef float    f32x4  __attribute__((ext_vector_type(4)));

#define WPLANE 1835008      // 256*7168 halves per plane

__device__ __forceinline__ _Float16 hi16(float f) { return (_Float16)f; }
__device__ __forceinline__ _Float16 lo16(float f) {
    _Float16 h = (_Float16)f;
    return (_Float16)(f - (float)h);
}

// ---------------- Kernel 0: split (W*1024) into fp16 hi/lo planes, CHUNK-MAJOR ----------------
// Layout: plane[(k>>5)*8192 + e*32 + (k&31)] -> per K-chunk, all 256 experts contiguous.
// Also zeroes the flagged-token counter (runs before gate_main on the stream).
__global__ __launch_bounds__(256)
void conv_w(const float* __restrict__ W, _Float16* __restrict__ Wh, _Float16* __restrict__ Wl,
            int* __restrict__ cnt) {
    if (blockIdx.x == 0 && threadIdx.x == 0) *cnt = 0;
    int i = blockIdx.x * 256 + threadIdx.x;       // over 458752 float4s (exact)
    int f = i * 4;
    int e = f / DIM;
    int k = f - e * DIM;
    float4 v = ((const float4*)W)[i];
    v.x *= WSCALE; v.y *= WSCALE; v.z *= WSCALE; v.w *= WSCALE;
    half4v h, l;
    h[0] = hi16(v.x); l[0] = lo16(v.x);
    h[1] = hi16(v.y); l[1] = lo16(v.y);
    h[2] = hi16(v.z); l[2] = lo16(v.z);
    h[3] = hi16(v.w); l[3] = lo16(v.w);
    int o = ((k >> 5) << 13) + (e << 5) + (k & 31);   // chunk-major offset
    *(half4v*)(Wh + o) = h;
    *(half4v*)(Wl + o) = l;
}

// ---------------- asm pipeline primitives (T3/T4: pinned issue order, counted waits) ----------------
#define MFMA16(a, b, c) __builtin_amdgcn_mfma_f32_16x16x32_f16(a, b, c, 0, 0, 0)

// counted vmcnt wait + scheduling fence (rule #18)
#define VWAIT(n) do { \
    asm volatile("s_waitcnt vmcnt(" #n ")" ::: "memory"); \
    __builtin_amdgcn_sched_barrier(0); \
} while (0)

// one W chunk (4 x dwordx4) into named register set S; issue order pinned by asm volatile.
// n=1 tile is +512 halves = +1024 B -> fits the 13-bit signed imm offset.
#define ISSUE_WS(c, S) do { \
    const _Float16* _p = wph0 + (size_t)(c) * 8192; \
    const _Float16* _q = wpl0 + (size_t)(c) * 8192; \
    asm volatile("global_load_dwordx4 %0, %1, off"             : "=&v"(S##h0) : "v"(_p)); \
    asm volatile("global_load_dwordx4 %0, %1, off offset:1024" : "=&v"(S##h1) : "v"(_p)); \
    asm volatile("global_load_dwordx4 %0, %1, off"             : "=&v"(S##l0) : "v"(_q)); \
    asm volatile("global_load_dwordx4 %0, %1, off offset:1024" : "=&v"(S##l1) : "v"(_q)); \
} while (0)

#define ISSUE_X(gg) do { \
    const float* _px = xsrc + (size_t)(gg) * 128; \
    asm volatile("global_load_dwordx4 %0, %1, off"           : "=&v"(xa) : "v"(_px)); \
    asm volatile("global_load_dwordx4 %0, %1, off offset:16" : "=&v"(xb) : "v"(_px)); \
} while (0)

// ds_read A-frags + 12 MFMA (T5 setprio around the cluster).
// Per-accumulator product order identical to the verified kernel.
#define COMPUTE(ABP, BH0, BH1, BL0, BL1) do { \
    const _Float16* _ab = (ABP); \
    half8 ah0 = *(const half8*)(_ab + abase0); \
    half8 ah1 = *(const half8*)(_ab + abase1); \
    half8 al0 = *(const half8*)(_ab + 2048 + abase0); \
    half8 al1 = *(const half8*)(_ab + 2048 + abase1); \
    __builtin_amdgcn_s_setprio(1); \
    acc00 = MFMA16(ah0, BH0, acc00); acc00 = MFMA16(ah0, BL0, acc00); acc00 = MFMA16(al0, BH0, acc00); \
    acc01 = MFMA16(ah0, BH1, acc01); acc01 = MFMA16(ah0, BL1, acc01); acc01 = MFMA16(al0, BH1, acc01); \
    acc10 = MFMA16(ah1, BH0, acc10); acc10 = MFMA16(ah1, BL0, acc10); acc10 = MFMA16(al1, BH0, acc10); \
    acc11 = MFMA16(ah1, BH1, acc11); acc11 = MFMA16(ah1, BL1, acc11); acc11 = MFMA16(al1, BH1, acc11); \
    __builtin_amdgcn_s_setprio(0); \
} while (0)

#define COMPUTE_S(ABP, S) COMPUTE(ABP, S##h0, S##h1, S##l0, S##l1)

#define DUMPF() do { \
    accf00 += acc00; acc00 = (f32x4)(0.0f); \
    accf01 += acc01; acc01 = (f32x4)(0.0f); \
    accf10 += acc10; acc10 = (f32x4)(0.0f); \
    accf11 += acc11; acc11 = (f32x4)(0.0f); \
} while (0)

#define CONVERT_WRITE_X(dstbuf) do { \
    half8 h8, l8; \
    const float v[8] = {xa.x, xa.y, xa.z, xa.w, xb.x, xb.y, xb.z, xb.w}; \
    _Pragma("unroll") \
    for (int e = 0; e < 8; ++e) { h8[e] = hi16(v[e]); l8[e] = lo16(v[e]); } \
    _Float16* d = hb + (dstbuf) * 16384 + xdst; \
    *(half8*)(d)        = h8; \
    *(half8*)(d + 2048) = l8; \
} while (0)

// ---------------- Kernel 1: fp16-split MFMA GEMM + routing + compacted flags ----------------
// 1024 threads (16 waves), [64 tokens] x [256 experts] per block, grid 256.
// DEPTH-3 W prefetch: 3 chunk-sets always in flight (12-14 loads). Issue->wait distance
// = 3 chunks (~700+ cyc of compute) >= L3 latency -> VWAITs retire instantly; VMEM return,
// LDS, and MFMA pipes overlap instead of lockstep-serializing (the R1/R2 failure mode).
// Steady-state queue entering a group: [W(c),W(c+1),W(c+2)] = 12 loads.
//   cc0: VWAIT(8)  -> W(c)  ready; issue W(c+3), X(g+1)   [queue 14]
//   cc1: VWAIT(10) -> W(c+1) ready; issue W(c+4)          [queue 14]
//   cc2: VWAIT(10) -> W(c+2) ready; issue W(c+5)          [queue 14]
//   cc3: VWAIT(10) -> W(c+3) ready; issue W(c+6)          [queue 14]
//   VWAIT(12) -> X ready; convert+write; lgkm drain; s_barrier (12 W-loads stay in flight).
// COMPUTE order / DUMPF cadence / convert identical -> logits bit-identical -> same flags.
__global__ __launch_bounds__(1024)
void gate_main(const float* __restrict__ X, const _Float16* __restrict__ Wh,
               const _Float16* __restrict__ Wl, const float* __restrict__ Bp,
               float* __restrict__ outw, float* __restrict__ outi,
               int* __restrict__ cnt, int* __restrict__ list) {
    __shared__ float smem[16384];                 // 64 KB: X dbuf (2 x 32 KB); routing overlay after
    _Float16* hb = (_Float16*)smem;

    const int tid  = threadIdx.x;
    const int lane = tid & 63;
    const int wid  = tid >> 6;                    // 0..15
    const int mh   = wid >> 3;                    // 0..1  (token half: 32 rows)
    const int ns   = wid & 7;                     // 0..7  (expert slice: 32 cols)
    const int m0   = blockIdx.x * BM;
    const int fr   = lane & 15;
    const int fk   = lane >> 4;                   // 0..3

    // X staging map: thread -> (chunk-in-group, row, 16B slot); XOR-swizzled dest
    const int xcc = tid >> 8;                     // 0..3
    const int xr  = (tid >> 2) & 63;              // 0..63
    const int xs  = tid & 3;                      // 0..3
    const float* xsrc = X + (size_t)(m0 + xr) * DIM + xcc * 32 + xs * 8;
    const int xdst = xcc * 4096 + xr * 32 + ((xs ^ ((xr >> 1) & 3)) << 3);

    // A-fragment LDS bases (halves), swizzled
    const int row0 = mh * 32 + fr;
    const int row1 = mh * 32 + 16 + fr;
    const int abase0 = row0 * 32 + ((fk ^ ((row0 >> 1) & 3)) << 3);
    const int abase1 = row1 * 32 + ((fk ^ ((row1 >> 1) & 3)) << 3);

    // W chunk-major per-lane base pointers; chunk c at +c*8192 halves; n=1 tile at +512 halves (imm)
    const int wro = ((ns * 32 + fr) << 5) + fk * 8;
    const _Float16* wph0 = Wh + wro;
    const _Float16* wpl0 = Wl + wro;

    f32x4 acc00 = {}, acc01 = {}, acc10 = {}, acc11 = {};
    f32x4 accf00 = {}, accf01 = {}, accf10 = {}, accf11 = {};
    half8 S0h0, S0h1, S0l0, S0l1;                 // W register sets (4 chunks, rotating)
    half8 S1h0, S1h1, S1l0, S1l1;
    half8 S2h0, S2h1, S2l0, S2l1;
    half8 S3h0, S3h1, S3l0, S3l1;
    float4 xa, xb;

    // ---- prologue: stage X group 0 (plain C++), drain, then pin W(0..2) in flight ----
    {
        float4 pa = *(const float4*)(xsrc);
        float4 pb = *(const float4*)(xsrc + 4);
        half8 h8, l8;
        const float v[8] = {pa.x, pa.y, pa.z, pa.w, pb.x, pb.y, pb.z, pb.w};
        #pragma unroll
        for (int e = 0; e < 8; ++e) { h8[e] = hi16(v[e]); l8[e] = lo16(v[e]); }
        *(half8*)(hb + xdst)        = h8;
        *(half8*)(hb + xdst + 2048) = l8;
    }
    asm volatile("s_waitcnt vmcnt(0) lgkmcnt(0)" ::: "memory");   // clean queue before asm issues
    __builtin_amdgcn_sched_barrier(0);
    ISSUE_WS(0, S0);
    ISSUE_WS(1, S1);
    ISSUE_WS(2, S2);
    __builtin_amdgcn_s_barrier();                 // buf0 visible; 12 W-loads in flight

    for (int g = 0; g < NGROUP - 1; ++g) {        // groups 0..54 (full pipeline)
        const _Float16* ab = hb + (g & 1) * 16384;
        const int c0 = g * 4;
        VWAIT(8);  ISSUE_WS(c0 + 3, S3); ISSUE_X(g + 1); COMPUTE_S(ab,         S0);
        VWAIT(10); ISSUE_WS(c0 + 4, S0);                 COMPUTE_S(ab + 4096,  S1);
        VWAIT(10); ISSUE_WS(c0 + 5, S1);                 COMPUTE_S(ab + 8192,  S2);
        VWAIT(10); ISSUE_WS(c0 + 6, S2);                 COMPUTE_S(ab + 12288, S3);
        if ((g & 3) == 3) DUMPF();                // fp32 master dump every 16 chunks (same cadence)
        VWAIT(12);                                // X(g+1) done (issued ~3 chunks ago)
        CONVERT_WRITE_X((g & 1) ^ 1);
        asm volatile("s_waitcnt lgkmcnt(0)" ::: "memory");
        __builtin_amdgcn_s_barrier();             // 12 W-loads stay in flight across barrier (T4)
    }
    {   // ---- epilogue group 55 (chunks 220..223, buf 1); queue entering: [W220,W221,W222] ----
        const _Float16* ab = hb + 16384;
        VWAIT(8); ISSUE_WS(223, S3); COMPUTE_S(ab,         S0);
        VWAIT(8);                    COMPUTE_S(ab + 4096,  S1);
        VWAIT(4);                    COMPUTE_S(ab + 8192,  S2);
        VWAIT(0);                    COMPUTE_S(ab + 12288, S3);
        DUMPF();                                  // g=55: (55&3)==3 -> same cadence
    }
    __syncthreads();                              // full drain before LDS overlay reuse

    // ---- logits (unscaled) to rotated LDS overlay ----
    float* lg = smem;                             // [64][256], word = t*256 + ((e+t)&255)
    {
        f32x4 af[2][2] = {{accf00, accf01}, {accf10, accf11}};
        #pragma unroll
        for (int m = 0; m < 2; ++m)
            #pragma unroll
            for (int n = 0; n < 2; ++n)
                #pragma unroll
                for (int r = 0; r < 4; ++r) {
                    int t = mh * 32 + m * 16 + fk * 4 + r;   // D row = (lane>>4)*4 + reg
                    int e = ns * 32 + n * 16 + fr;           // D col = lane&15
                    lg[t * 256 + ((e + t) & 255)] = af[m][n][r] * WUNSCALE;
                }
    }
    __syncthreads();

    // ---- fp32 routing + margin flags: one thread per token (R4/R7-verified, verbatim) ----
    if (tid < BM) {
        const int t = tid;
        const int gtok = m0 + t;
        float* row = lg + t * 256;

        for (int e = 0; e < 256; ++e) {
            int a = (e + t) & 255;
            row[a] = 1.0f / (1.0f + expf(-row[a]));
        }
        float gs[8];
        #pragma unroll
        for (int g = 0; g < 8; ++g) {
            float m1 = -FLT_MAX, m2 = -FLT_MAX;
            for (int e = g * 32; e < g * 32 + 32; ++e) {
                float v = row[(e + t) & 255] + Bp[e];
                if (v > m1) { m2 = m1; m1 = v; }
                else if (v > m2) { m2 = v; }
            }
            gs[g] = m1 + m2;
        }
        unsigned sel = 0;
        #pragma unroll
        for (int r = 0; r < 4; ++r) {
            float best = -FLT_MAX; int bg = 0;
            #pragma unroll
            for (int g = 0; g < 8; ++g)
                if (!((sel >> g) & 1) && gs[g] > best) { best = gs[g]; bg = g; }
            sel |= 1u << bg;
        }
        float selmin = FLT_MAX, unselmax = -FLT_MAX;
        #pragma unroll
        for (int g = 0; g < 8; ++g) {
            if ((sel >> g) & 1) selmin = fminf(selmin, gs[g]);
            else                unselmax = fmaxf(unselmax, gs[g]);
        }
        bool flag = (selmin - unselmax) < (2.0f * TAU);

        float pv = FLT_MAX; int pe = -1;
        float wv8[8]; int ie8[8]; float wsum = 0.f;
        for (int j = 0; j < 9; ++j) {
            float best = -FLT_MAX; int be = 0;
            for (int e = 0; e < 256; ++e) {
                float v = ((sel >> (e >> 5)) & 1) ? (row[(e + t) & 255] + Bp[e]) : 0.0f;
                bool after = (v < pv) || (v == pv && e > pe);
                if (after && v > best) { best = v; be = e; }
            }
            if (j > 0) flag = flag || ((pv - best) < TAU);
            if (j < 8) {
                float ow = row[(be + t) & 255];
                wv8[j] = ow; ie8[j] = be; wsum += ow;
            }
            pv = best; pe = be;
        }
        if (flag) {                                // compacted flag list (device-scope atomic)
            int slot = atomicAdd(cnt, 1);
            list[slot] = gtok;
        }
        float scale = (float)ROUTE_SCALE / wsum;
        #pragma unroll
        for (int j = 0; j < 8; ++j) {
            outw[(size_t)gtok * 8 + j] = wv8[j] * scale;
            outi[(size_t)gtok * 8 + j] = (float)ie8[j];
        }
    }
}

// ---------------- Kernel 2: fp64 recheck of flagged tokens (compacted list, grid-stride) ----------------
// 256 blocks grid-stride the compacted list; per-token inner math verbatim from verified kernel.
__global__ __launch_bounds__(256)
void gate_fix(const float* __restrict__ X, const float* __restrict__ W,
              const float* __restrict__ Bp, float* __restrict__ outw,
              float* __restrict__ outi, const int* __restrict__ cnt,
              const int* __restrict__ list) {
    __shared__ float  xrow[DIM];
    __shared__ double sig[NEXP];
    const int tid = threadIdx.x;
    const int s   = tid >> 5;
    const int kt  = tid & 31;
    const int n   = *cnt;

    for (int li = blockIdx.x; li < n; li += 256) {
        const int t = list[li];
        __syncthreads();                          // previous iteration's readers done

        for (int i = tid * 4; i < DIM; i += 1024)
            *(float4*)(xrow + i) = *(const float4*)(X + (size_t)t * DIM + i);
        __syncthreads();

        for (int i = 0; i < 32; ++i) {
            const int e = i * 8 + s;
            const float* wrow = W + (size_t)e * DIM;
            double s0 = 0, s1 = 0, s2 = 0, s3 = 0;
            for (int c = 0; c < DIM / 128; ++c) {
                int k = c * 128 + kt * 4;
                float4 w4 = *(const float4*)(wrow + k);
                float4 x4 = *(const float4*)(xrow + k);
                s0 = fma((double)x4.x, (double)w4.x, s0);
                s1 = fma((double)x4.y, (double)w4.y, s1);
                s2 = fma((double)x4.z, (double)w4.z, s2);
                s3 = fma((double)x4.w, (double)w4.w, s3);
            }
            double d = (s0 + s1) + (s2 + s3);
            #pragma unroll
            for (int m = 16; m >= 1; m >>= 1)
                d += __shfl_xor(d, m, 32);
            if (kt == 0) sig[e] = 1.0 / (1.0 + exp(-d));
        }
        __syncthreads();

        if (tid == 0) {
            const double* row = sig;
            double gs[8];
            #pragma unroll
            for (int g = 0; g < 8; ++g) {
                double m1 = -DBL_MAX, m2 = -DBL_MAX;
                for (int e = g * 32; e < g * 32 + 32; ++e) {
                    double v = row[e] + (double)Bp[e];
                    if (v > m1) { m2 = m1; m1 = v; }
                    else if (v > m2) { m2 = v; }
                }
                gs[g] = m1 + m2;
            }
            unsigned sel = 0;
            #pragma unroll
            for (int r = 0; r < 4; ++r) {
                double best = -DBL_MAX; int bg = 0;
                #pragma unroll
                for (int g = 0; g < 8; ++g)
                    if (!((sel >> g) & 1) && gs[g] > best) { best = gs[g]; bg = g; }
                sel |= 1u << bg;
            }
            double pv = DBL_MAX; int pe = -1;
            double wv8[8]; int ie8[8]; double wsum = 0.0;
            #pragma unroll
            for (int j = 0; j < 8; ++j) {
                double best = -DBL_MAX; int be = 0;
                for (int e = 0; e < 256; ++e) {
                    double v = ((sel >> (e >> 5)) & 1) ? (row[e] + (double)Bp[e]) : 0.0;
                    bool after = (v < pv) || (v == pv && e > pe);
                    if (after && v > best) { best = v; be = e; }
                }
                double ow = row[be];
                wv8[j] = ow; ie8[j] = be; wsum += ow;
                pv = best; pe = be;
            }
            #pragma unroll
            for (int j = 0; j < 8; ++j) {
                outw[(size_t)t * 8 + j] = (float)((wv8[j] / wsum) * ROUTE_SCALE);
                outi[(size_t)t * 8 + j] = (float)ie8[j];
            }
        }
    }
}

extern "C" void kernel_launch(void* const* d_in, const int* in_sizes, int n_in,
                              void* d_out, int out_size, void* d_ws, size_t ws_size,
                              hipStream_t stream) {
    const float* X  = (const float*)d_in[0];
    const float* W  = (const float*)d_in[1];
    const float* Bp = (const float*)d_in[2];
    float* outw = (float*)d_out;
    float* outi = (float*)d_out + (size_t)TOKENS * 8;

    _Float16* Wh = (_Float16*)d_ws;                          // 3.67 MB (chunk-major)
    _Float16* Wl = Wh + WPLANE;                              // 3.67 MB (chunk-major)
    int* cnt  = (int*)(Wl + WPLANE);                         // 4 B
    int* list = cnt + 1;                                     // 64 KB

    conv_w   <<<dim3(WPLANE / 1024), dim3(256),  0, stream>>>(W, Wh, Wl, cnt);
    gate_main<<<dim3(TOKENS / BM),   dim3(1024), 0, stream>>>(X, Wh, Wl, Bp, outw, outi, cnt, list);
    gate_fix <<<dim3(256),           dim3(256),  0, stream>>>(X, W, Bp, outw, outi, cnt, list);
}